// Round 3
// baseline (395.851 us; speedup 1.0000x reference)
//
#include <hip/hip_runtime.h>
#include <math.h>

// Problem constants
#define T_DIM 16
#define B_DIM 128
#define N_DIM 2048
#define TB    (T_DIM * B_DIM)   // 2048 rows of the GEMM

// Workspace layout (bytes). h is f32 (16MB used of 32MB reserved).
#define WS_H      0
#define WS_PSUM   35651584      // [32][2048] f64 per-rowband col sums
#define WS_PSUM2  36175872      // [32][2048] f64 per-rowband col sq-sums
#define WS_SSUM   36700160      // [2048] f64 row sums

typedef __attribute__((ext_vector_type(4))) double d4;

// ---- MFMA f64 wiring probe helpers ----------------------------------------
__device__ __forceinline__ double probeA(int m, int k) {
    return (double)((m * 7 + k * 13) % 23 - 11);
}
__device__ __forceinline__ double probeB(int k, int n) {
    return (double)((k * 5 + n * 3) % 19 - 9);
}

// In-kernel probe: every block derives the MFMA wiring hypothesis itself
// (removes the separate probe launch + flag round-trip; ~0.4us per block).
// Hypothesis encoding fh = ab*4 + dF;  ab = aF + 2*bF.
//  A-form 0: m=l&15,k=l>>4   1: m=l>>2,k=l&3
//  B-form 0: n=l&15,k=l>>4   1: n=l>>2,k=l&3
//  D-form 0: i=4*(l>>4)+r,j=l&15   1: i=(l>>4)+4r,j=l&15
//         2: j=4*(l>>4)+r,i=l&15   3: j=(l>>4)+4r,i=l&15
__device__ unsigned int run_probe(double* Cref, int l) {
    int i0 = l >> 2, j0 = (l & 3) << 2;
    for (int jj = 0; jj < 4; ++jj) {
        double s = 0.0;
        for (int k = 0; k < 4; ++k) s += probeA(i0, k) * probeB(k, j0 + jj);
        Cref[i0 * 16 + j0 + jj] = s;
    }
    __syncthreads();
    unsigned int win = 0xFFFFFFFFu;
    for (int ab = 0; ab < 4; ++ab) {
        int aF = ab & 1, bF = (ab >> 1) & 1;
        int mA = aF ? (l >> 2) : (l & 15);
        int kA = aF ? (l & 3)  : (l >> 4);
        int nB = bF ? (l >> 2) : (l & 15);
        int kB = bF ? (l & 3)  : (l >> 4);
        d4 d = (d4)0.0;
        d = __builtin_amdgcn_mfma_f64_16x16x4f64(probeA(mA, kA), probeB(kB, nB), d, 0, 0, 0);
        for (int dF = 0; dF < 4; ++dF) {
            double err = 0.0;
            for (int r = 0; r < 4; ++r) {
                int ii, jj;
                if (dF == 0)      { ii = 4 * (l >> 4) + r; jj = l & 15; }
                else if (dF == 1) { ii = (l >> 4) + 4 * r; jj = l & 15; }
                else if (dF == 2) { jj = 4 * (l >> 4) + r; ii = l & 15; }
                else              { jj = (l >> 4) + 4 * r; ii = l & 15; }
                err = fmax(err, fabs(d[r] - Cref[ii * 16 + jj]));
            }
            for (int off = 1; off < 64; off <<= 1)
                err = fmax(err, __shfl_xor(err, off, 64));
            if (err < 1e-9 && win == 0xFFFFFFFFu)
                win = (unsigned)(ab * 4 + dF);
        }
    }
    return win;
}

// ---- GEMM h[row,m] = sum_n x[row,n] * W[m,n] ------------------------------
// v13: all-MFMA 64x64 tile, 2 waves, in-block split-K (R2 proven structure)
// with three changes:
//  (1) [m][k] LDS layout, row stride 20 floats (16B-aligned rows): staging is
//      16x ds_write_b128 per iter instead of 128x ds_write_b32. Column XOR
//      swizzle (j ^ ((row>>3)&3)) keeps writes AND fragment reads at <=2-way
//      bank aliasing (free). Read offsets precomputed per-lane (static idx).
//      Theory: staging phases of the lockstep waves align in time; shrinking
//      them 8x recovers the matrix-pipe idle (MfmaUtil 78 -> ~86%).
//  (2) s_setprio(1) around MFMA bursts (waves are barrier-free/independent).
//  (3) probe + ssum folded in (blockIdx.x==0 blocks accumulate row sums at
//      stage time, where vmcnt is already drained).
#define BK 16
#define SK 20     // [m][k] row stride in floats (80B, 16B-aligned)
#define SDD 68    // f64 vector-fallback stride (doubles)

#define MFMA_LOAD(koff)                                             \
    _Pragma("unroll")                                               \
    for (int j = 0; j < 4; ++j) {                                   \
        sa[j] = *(const float4*)(Ag + (koff) + 4 * j);              \
        sb[j] = *(const float4*)(Bg + (koff) + 4 * j);              \
    }

#define MFMA_STAGE(Ab, Bb)                                          \
    _Pragma("unroll")                                               \
    for (int j = 0; j < 4; ++j) {                                   \
        *(float4*)&(Ab)[lane * SK + 4 * (j ^ swz)] = sa[j];         \
        *(float4*)&(Bb)[lane * SK + 4 * (j ^ swz)] = sb[j];         \
    }                                                               \
    if (do_rsum) {                                                  \
        _Pragma("unroll")                                           \
        for (int j = 0; j < 4; ++j)                                 \
            rsum += (double)sa[j].x + (double)sa[j].y +             \
                    (double)sa[j].z + (double)sa[j].w;              \
    }

#define MFMA_COMPUTE(Ab, Bb)                                        \
    _Pragma("unroll")                                               \
    for (int jq = 0; jq < 4; ++jq) {                                \
        double av[4], bv[4];                                        \
        _Pragma("unroll")                                           \
        for (int f = 0; f < 4; ++f)                                 \
            av[f] = (double)(Ab)[aoff[f][jq]];                      \
        _Pragma("unroll")                                           \
        for (int g = 0; g < 4; ++g)                                 \
            bv[g] = (double)(Bb)[boff[g][jq]];                      \
        _Pragma("unroll")                                           \
        for (int f = 0; f < 4; ++f)                                 \
            _Pragma("unroll")                                       \
            for (int g = 0; g < 4; ++g)                             \
                acc[f][g] = __builtin_amdgcn_mfma_f64_16x16x4f64(   \
                    av[f], bv[g], acc[f][g], 0, 0, 0);              \
    }

__global__ __launch_bounds__(128, 2)
void gemm_hybrid(const float* __restrict__ A, const float* __restrict__ Bw,
                 float* __restrict__ C, double* __restrict__ psum,
                 double* __restrict__ psum2, double* __restrict__ ssum_out) {
    __shared__ __align__(16) char smem[40960];   // staging 2w x 4buf x 5120B; cbuf 32KB
    const int t    = threadIdx.x;
    const int lane = t & 63;
    const int w    = t >> 6;
    const int row0 = blockIdx.y * 64;
    const int col0 = blockIdx.x * 64;
    const int band = blockIdx.y;
    const bool do_rsum = (blockIdx.x == 0);

    // in-block probe (uses cbuf region; dead before staging starts)
    const unsigned int fh = run_probe((double*)smem, lane);
    __syncthreads();

    const float* Ag = A  + (size_t)(row0 + lane) * N_DIM;
    const float* Bg = Bw + (size_t)(col0 + lane) * N_DIM;
    const int kw = w * BK;
    double* cbuf = (double*)smem;                // 4096 doubles = 32KB
    double* rbuf = (double*)(smem + 32768);      // 64 doubles (row-sum xchg)
    double rsum = 0.0;

    if (fh <= 15u) {
        // ================= MFMA path =================
        const int dF = fh & 3, ab = fh >> 2;
        const int aF = ab & 1, bF = (ab >> 1) & 1;
        const int mA = aF ? (lane >> 2) : (lane & 15);
        const int kA = aF ? (lane & 3)  : (lane >> 4);
        const int nB = bF ? (lane >> 2) : (lane & 15);
        const int kB = bF ? (lane & 3)  : (lane >> 4);
        const int swz = (lane >> 3) & 3;
        int iD[4], jD[4];
#pragma unroll
        for (int r = 0; r < 4; ++r) {
            if (dF == 0)      { iD[r] = 4 * (lane >> 4) + r; jD[r] = lane & 15; }
            else if (dF == 1) { iD[r] = (lane >> 4) + 4 * r; jD[r] = lane & 15; }
            else if (dF == 2) { jD[r] = 4 * (lane >> 4) + r; iD[r] = lane & 15; }
            else              { jD[r] = (lane >> 4) + 4 * r; iD[r] = lane & 15; }
        }
        // precomputed fragment-read offsets (swizzle-aware, loop-invariant)
        int aoff[4][4], boff[4][4];
#pragma unroll
        for (int f = 0; f < 4; ++f)
#pragma unroll
            for (int jq = 0; jq < 4; ++jq) {
                int am = 16 * f + mA;
                aoff[f][jq] = am * SK + 4 * (jq ^ ((am >> 3) & 3)) + kA;
                int bn = 16 * f + nB;
                boff[f][jq] = bn * SK + 4 * (jq ^ ((bn >> 3) & 3)) + kB;
            }

        float* A0 = (float*)(smem + (size_t)w * 20480);  // 64 x SK floats
        float* B0 = A0 + 1280;
        float* A1 = A0 + 2560;
        float* B1 = A0 + 3840;

        d4 acc[4][4];
#pragma unroll
        for (int f = 0; f < 4; ++f)
#pragma unroll
            for (int g = 0; g < 4; ++g) acc[f][g] = (d4)0.0;

        float4 sa[4], sb[4];
        MFMA_LOAD(kw)                 // tile 0
        MFMA_STAGE(A0, B0)            // -> buf0
        MFMA_LOAD(kw + 32)            // tile 1

        for (int k0 = kw; k0 < N_DIM; k0 += 64) {
            MFMA_STAGE(A1, B1)        // tile k0+32 -> buf1
            if (k0 + 64 < N_DIM) { MFMA_LOAD(k0 + 64) }
            __builtin_amdgcn_s_setprio(1);
            MFMA_COMPUTE(A0, B0)      // tile k0
            __builtin_amdgcn_s_setprio(0);
            if (k0 + 64 < N_DIM) {
                MFMA_STAGE(A0, B0)    // tile k0+64 -> buf0
                if (k0 + 96 < N_DIM) { MFMA_LOAD(k0 + 96) }
            }
            __builtin_amdgcn_s_setprio(1);
            MFMA_COMPUTE(A1, B1)      // tile k0+32
            __builtin_amdgcn_s_setprio(0);
        }

        __syncthreads();
        if (w == 1) {
#pragma unroll
            for (int f = 0; f < 4; ++f)
#pragma unroll
                for (int g = 0; g < 4; ++g)
#pragma unroll
                    for (int r = 0; r < 4; ++r)
                        cbuf[((f * 4 + g) * 4 + r) * 64 + lane] = acc[f][g][r];
            if (do_rsum) rbuf[lane] = rsum;
        }
        __syncthreads();
        if (w == 0) {
#pragma unroll
            for (int f = 0; f < 4; ++f)
#pragma unroll
                for (int g = 0; g < 4; ++g)
#pragma unroll
                    for (int r = 0; r < 4; ++r)
                        acc[f][g][r] += cbuf[((f * 4 + g) * 4 + r) * 64 + lane];
            // store C (f32)
#pragma unroll
            for (int f = 0; f < 4; ++f)
#pragma unroll
                for (int r = 0; r < 4; ++r) {
                    int row = row0 + 16 * f + iD[r];
                    float* Crow = C + (size_t)row * N_DIM + col0 + jD[r];
#pragma unroll
                    for (int g = 0; g < 4; ++g)
                        Crow[16 * g] = (float)acc[f][g][r];
                }
            // layout-agnostic BN partials: scatter acc -> cbuf[row][col],
            // then column-sum (same-wave DS ordering -> no barrier needed)
#pragma unroll
            for (int f = 0; f < 4; ++f)
#pragma unroll
                for (int r = 0; r < 4; ++r)
#pragma unroll
                    for (int g = 0; g < 4; ++g)
                        cbuf[(16 * f + iD[r]) * 64 + 16 * g + jD[r]] = acc[f][g][r];
            double s = 0.0, q = 0.0;
#pragma unroll
            for (int r = 0; r < 64; ++r) {
                double v = cbuf[r * 64 + lane];
                s += v;
                q = fma(v, v, q);
            }
            psum [band * N_DIM + col0 + lane] = s;
            psum2[band * N_DIM + col0 + lane] = q;
            if (do_rsum) ssum_out[row0 + lane] = rsum + rbuf[lane];
        }
    } else {
        // ================= f64 VALU fallback (probe-fail only) =================
        const int tx = lane & 7;
        const int ty = lane >> 3;
        double* Asd = (double*)smem + (size_t)w * 2176;  // 16 x 68 doubles
        double* Bsd = Asd + 1088;

        double acc[8][8];
#pragma unroll
        for (int i = 0; i < 8; ++i)
#pragma unroll
            for (int j = 0; j < 8; ++j) acc[i][j] = 0.0;

        float4 sa[4], sb[4];
#pragma unroll
        for (int j = 0; j < 4; ++j) {
            sa[j] = *(const float4*)(Ag + kw + 4 * j);
            sb[j] = *(const float4*)(Bg + kw + 4 * j);
        }
        for (int k0 = kw; k0 < N_DIM; k0 += 2 * BK) {
#pragma unroll
            for (int j = 0; j < 4; ++j) {
                Asd[(4 * j + 0) * SDD + lane] = (double)sa[j].x;
                Asd[(4 * j + 1) * SDD + lane] = (double)sa[j].y;
                Asd[(4 * j + 2) * SDD + lane] = (double)sa[j].z;
                Asd[(4 * j + 3) * SDD + lane] = (double)sa[j].w;
                Bsd[(4 * j + 0) * SDD + lane] = (double)sb[j].x;
                Bsd[(4 * j + 1) * SDD + lane] = (double)sb[j].y;
                Bsd[(4 * j + 2) * SDD + lane] = (double)sb[j].z;
                Bsd[(4 * j + 3) * SDD + lane] = (double)sb[j].w;
            }
            if (do_rsum) {
#pragma unroll
                for (int j = 0; j < 4; ++j)
                    rsum += (double)sa[j].x + (double)sa[j].y +
                            (double)sa[j].z + (double)sa[j].w;
            }
            if (k0 + 2 * BK < N_DIM) {
#pragma unroll
                for (int j = 0; j < 4; ++j) {
                    sa[j] = *(const float4*)(Ag + k0 + 2 * BK + 4 * j);
                    sb[j] = *(const float4*)(Bg + k0 + 2 * BK + 4 * j);
                }
            }
#pragma unroll
            for (int k = 0; k < BK; ++k) {
                double a[8], b[8];
#pragma unroll
                for (int e = 0; e < 4; ++e) {
                    a[e]     = Asd[k * SDD + 4 * ty + e];
                    a[e + 4] = Asd[k * SDD + 32 + 4 * ty + e];
                    b[e]     = Bsd[k * SDD + 4 * tx + e];
                    b[e + 4] = Bsd[k * SDD + 32 + 4 * tx + e];
                }
#pragma unroll
                for (int i = 0; i < 8; ++i)
#pragma unroll
                    for (int j = 0; j < 8; ++j)
                        acc[i][j] = fma(a[i], b[j], acc[i][j]);
            }
        }

        __syncthreads();
        if (w == 1) {
#pragma unroll
            for (int e = 0; e < 64; ++e)
                cbuf[e * 64 + lane] = acc[e >> 3][e & 7];
            if (do_rsum) rbuf[lane] = rsum;
        }
        __syncthreads();
        if (w == 0) {
#pragma unroll
            for (int i = 0; i < 8; ++i)
#pragma unroll
                for (int j = 0; j < 8; ++j)
                    acc[i][j] += cbuf[(i * 8 + j) * 64 + lane];
#pragma unroll
            for (int i = 0; i < 8; ++i) {
                int r = row0 + ((i < 4) ? (4 * ty + i) : (32 + 4 * ty + i - 4));
                float* Crow = C + (size_t)r * N_DIM + col0;
#pragma unroll
                for (int jg = 0; jg < 2; ++jg) {
                    int cbase = (jg == 0) ? (4 * tx) : (32 + 4 * tx);
                    float4 v;
                    v.x = (float)acc[i][4 * jg + 0]; v.y = (float)acc[i][4 * jg + 1];
                    v.z = (float)acc[i][4 * jg + 2]; v.w = (float)acc[i][4 * jg + 3];
                    *(float4*)(Crow + cbase) = v;
                }
            }
            // BN partials via cbuf scatter + column reduction
#pragma unroll
            for (int i = 0; i < 8; ++i) {
                int rr = (i < 4) ? (4 * ty + i) : (32 + 4 * ty + i - 4);
#pragma unroll
                for (int j = 0; j < 8; ++j) {
                    int cc = (j < 4) ? (4 * tx + j) : (32 + 4 * tx + j - 4);
                    cbuf[rr * 64 + cc] = acc[i][j];
                }
            }
            double s = 0.0, q = 0.0;
#pragma unroll
            for (int r = 0; r < 64; ++r) {
                double v = cbuf[r * 64 + lane];
                s += v;
                q = fma(v, v, q);
            }
            psum [band * N_DIM + col0 + lane] = s;
            psum2[band * N_DIM + col0 + lane] = q;
            if (do_rsum) ssum_out[row0 + lane] = rsum + rbuf[lane];
        }
    }
}

// ---- fused BN-final + BN-apply + temporal-sum + triple LIF + output -------
// Absorbs col_stats_final (scale/shift re-derived per thread from the
// L2-resident 1MB psum/psum2) and temporal_sum (computed from the x values
// this thread must load anyway; x cached in 16 regs, killing the re-read).
__global__ __launch_bounds__(256)
void fused_lif_kernel(const float* __restrict__ x, const float* __restrict__ h,
                      const double* __restrict__ psum, const double* __restrict__ psum2,
                      const float* __restrict__ gamma, const float* __restrict__ beta,
                      const double* __restrict__ ssum, float* __restrict__ out) {
    int idx = blockIdx.x * 256 + threadIdx.x;
    int n = idx & (N_DIM - 1);
    int b = idx >> 11;
    // BN scale/shift for this column
    double s = 0.0, s2 = 0.0;
#pragma unroll
    for (int c = 0; c < 32; ++c) {
        s  += psum [c * N_DIM + n];
        s2 += psum2[c * N_DIM + n];
    }
    double mean = s * (1.0 / 2048.0);
    double var  = s2 * (1.0 / 2048.0) - mean * mean;
    double istd = 1.0 / sqrt(var + 1e-5);
    double sc = istd * (double)gamma[n];
    double sh = (double)beta[n] - mean * sc;
    // temporal sum (ascending t, f64 -- same order as the old tsum kernel)
    float xv[T_DIM];
    double ts = 0.0;
#pragma unroll
    for (int t = 0; t < T_DIM; ++t) {
        xv[t] = x[(size_t)(t * B_DIM + b) * N_DIM + n];
        ts += (double)xv[t];
    }
    double v1 = 0.0, v2 = 0.0, v3 = 0.0;
#pragma unroll
    for (int t = 0; t < T_DIM; ++t) {
        size_t off = (size_t)(t * B_DIM + b) * N_DIM + n;
        double hv = fma((double)h[off], sc, sh);
        v1 = v1 * 0.5 + hv;
        bool s1 = (v1 >= 1.0); if (s1) v1 = 0.0;
        double in2 = s1 ? ssum[t * B_DIM + b] : 0.0;
        v2 = v2 * 0.5 + in2;
        bool s2b = (v2 >= 1.0); if (s2b) v2 = 0.0;
        double in3 = s1 ? ts : 0.0;
        v3 = v3 * 0.5 + in3;
        bool s3 = (v3 >= 1.0); if (s3) v3 = 0.0;
        out[off] = xv[t] + ((s2b && s3) ? 1.0f : 0.0f);
    }
}

extern "C" void kernel_launch(void* const* d_in, const int* in_sizes, int n_in,
                              void* d_out, int out_size, void* d_ws, size_t ws_size,
                              hipStream_t stream) {
    const float* x     = (const float*)d_in[0];   // [16,128,2048]
    const float* W     = (const float*)d_in[1];   // [2048,2048]
    const float* gamma = (const float*)d_in[2];   // [2048]
    const float* beta  = (const float*)d_in[3];   // [2048]
    float* out = (float*)d_out;

    char* ws = (char*)d_ws;
    float*  h     = (float*)(ws + WS_H);
    double* psum  = (double*)(ws + WS_PSUM);
    double* psum2 = (double*)(ws + WS_PSUM2);
    double* ssum  = (double*)(ws + WS_SSUM);

    gemm_hybrid<<<dim3(N_DIM / 64, TB / 64), 128, 0, stream>>>(x, W, h, psum, psum2, ssum);
    fused_lif_kernel<<<(B_DIM * N_DIM) / 256, 256, 0, stream>>>(
        x, h, psum, psum2, gamma, beta, ssum, out);
}

// Round 4
// 365.364 us; speedup vs baseline: 1.0834x; 1.0834x over previous
//
#include <hip/hip_runtime.h>
#include <math.h>

// Problem constants
#define T_DIM 16
#define B_DIM 128
#define N_DIM 2048
#define TB    (T_DIM * B_DIM)   // 2048 rows of the GEMM

// Workspace layout (bytes). h is f32 (16MB used of 32MB reserved).
#define WS_H      0
#define WS_PSUM   35651584      // [32][2048] f64 per-rowband col sums
#define WS_PSUM2  36175872      // [32][2048] f64 per-rowband col sq-sums
#define WS_SSUM   36700160      // [2048] f64 row sums

typedef __attribute__((ext_vector_type(4))) double d4;

// ---- MFMA f64 wiring probe helpers ----------------------------------------
__device__ __forceinline__ double probeA(int m, int k) {
    return (double)((m * 7 + k * 13) % 23 - 11);
}
__device__ __forceinline__ double probeB(int k, int n) {
    return (double)((k * 5 + n * 3) % 19 - 9);
}

// In-kernel probe: every block derives the MFMA wiring hypothesis itself.
// Hypothesis encoding fh = ab*4 + dF;  ab = aF + 2*bF.
//  A-form 0: m=l&15,k=l>>4   1: m=l>>2,k=l&3
//  B-form 0: n=l&15,k=l>>4   1: n=l>>2,k=l&3
//  D-form 0: i=4*(l>>4)+r,j=l&15   1: i=(l>>4)+4r,j=l&15
//         2: j=4*(l>>4)+r,i=l&15   3: j=(l>>4)+4r,i=l&15
__device__ unsigned int run_probe(double* Cref, int l) {
    int i0 = l >> 2, j0 = (l & 3) << 2;
    for (int jj = 0; jj < 4; ++jj) {
        double s = 0.0;
        for (int k = 0; k < 4; ++k) s += probeA(i0, k) * probeB(k, j0 + jj);
        Cref[i0 * 16 + j0 + jj] = s;
    }
    __syncthreads();
    unsigned int win = 0xFFFFFFFFu;
    for (int ab = 0; ab < 4; ++ab) {
        int aF = ab & 1, bF = (ab >> 1) & 1;
        int mA = aF ? (l >> 2) : (l & 15);
        int kA = aF ? (l & 3)  : (l >> 4);
        int nB = bF ? (l >> 2) : (l & 15);
        int kB = bF ? (l & 3)  : (l >> 4);
        d4 d = (d4)0.0;
        d = __builtin_amdgcn_mfma_f64_16x16x4f64(probeA(mA, kA), probeB(kB, nB), d, 0, 0, 0);
        for (int dF = 0; dF < 4; ++dF) {
            double err = 0.0;
            for (int r = 0; r < 4; ++r) {
                int ii, jj;
                if (dF == 0)      { ii = 4 * (l >> 4) + r; jj = l & 15; }
                else if (dF == 1) { ii = (l >> 4) + 4 * r; jj = l & 15; }
                else if (dF == 2) { jj = 4 * (l >> 4) + r; ii = l & 15; }
                else              { jj = (l >> 4) + 4 * r; ii = l & 15; }
                err = fmax(err, fabs(d[r] - Cref[ii * 16 + jj]));
            }
            for (int off = 1; off < 64; off <<= 1)
                err = fmax(err, __shfl_xor(err, off, 64));
            if (err < 1e-9 && win == 0xFFFFFFFFu)
                win = (unsigned)(ab * 4 + dF);
        }
    }
    return win;
}

// ---- GEMM h[row,m] = sum_n x[row,n] * W[m,n] ------------------------------
// v14: CONSOLIDATION. GEMM internals reverted EXACTLY to the R2-proven
// structure (292us, MfmaUtil 78%, 0 bank conflicts): [k][m] LDS layout with
// stride 80 floats, scalar ds_write_b32 staging, inline fragment addressing,
// no setprio. R3's [m][k]+precomputed-offsets variant regressed: 8.9M LDS
// bank conflicts (read-side 4-way aliasing at stride 20) + 213MB scratch
// traffic (32 live offset regs on top of 128 acc AGPRs -> spill).
// KEPT from R3 (validated, tail 76->60us): in-kernel probe, row-sum (ssum)
// accumulated at stage time, f32 h store, 2-launch pipeline.
#define BK 16
#define STRD 80   // [k][m] stride in floats (2-way bank aliasing = free)
#define SDD 68    // f64 vector-fallback stride (doubles)

#define MFMA_LOAD(koff)                                             \
    _Pragma("unroll")                                               \
    for (int j = 0; j < 4; ++j) {                                   \
        sa[j] = *(const float4*)(Ag + (koff) + 4 * j);              \
        sb[j] = *(const float4*)(Bg + (koff) + 4 * j);              \
    }

#define MFMA_STAGE(Ab, Bb)                                          \
    _Pragma("unroll")                                               \
    for (int j = 0; j < 4; ++j) {                                   \
        (Ab)[(4 * j + 0) * STRD + lane] = sa[j].x;                  \
        (Ab)[(4 * j + 1) * STRD + lane] = sa[j].y;                  \
        (Ab)[(4 * j + 2) * STRD + lane] = sa[j].z;                  \
        (Ab)[(4 * j + 3) * STRD + lane] = sa[j].w;                  \
        (Bb)[(4 * j + 0) * STRD + lane] = sb[j].x;                  \
        (Bb)[(4 * j + 1) * STRD + lane] = sb[j].y;                  \
        (Bb)[(4 * j + 2) * STRD + lane] = sb[j].z;                  \
        (Bb)[(4 * j + 3) * STRD + lane] = sb[j].w;                  \
    }                                                               \
    if (do_rsum) {                                                  \
        _Pragma("unroll")                                           \
        for (int j = 0; j < 4; ++j)                                 \
            rsum += (double)sa[j].x + (double)sa[j].y +             \
                    (double)sa[j].z + (double)sa[j].w;              \
    }

#define MFMA_COMPUTE(Ab, Bb)                                        \
    _Pragma("unroll")                                               \
    for (int jq = 0; jq < 4; ++jq) {                                \
        double av[4], bv[4];                                        \
        _Pragma("unroll")                                           \
        for (int f = 0; f < 4; ++f)                                 \
            av[f] = (double)(Ab)[(4 * jq + kA) * STRD + 16 * f + mA]; \
        _Pragma("unroll")                                           \
        for (int g = 0; g < 4; ++g)                                 \
            bv[g] = (double)(Bb)[(4 * jq + kB) * STRD + 16 * g + nB]; \
        _Pragma("unroll")                                           \
        for (int f = 0; f < 4; ++f)                                 \
            _Pragma("unroll")                                       \
            for (int g = 0; g < 4; ++g)                             \
                acc[f][g] = __builtin_amdgcn_mfma_f64_16x16x4f64(   \
                    av[f], bv[g], acc[f][g], 0, 0, 0);              \
    }

__global__ __launch_bounds__(128, 2)
void gemm_hybrid(const float* __restrict__ A, const float* __restrict__ Bw,
                 float* __restrict__ C, double* __restrict__ psum,
                 double* __restrict__ psum2, double* __restrict__ ssum_out) {
    __shared__ __align__(16) char smem[40960];   // 2 waves x 2 bufs x 10240B; cbuf 32KB
    const int t    = threadIdx.x;
    const int lane = t & 63;
    const int w    = t >> 6;
    const int row0 = blockIdx.y * 64;
    const int col0 = blockIdx.x * 64;
    const int band = blockIdx.y;
    const bool do_rsum = (blockIdx.x == 0);

    // in-block probe (uses cbuf region; dead before staging starts)
    const unsigned int fh = run_probe((double*)smem, lane);
    __syncthreads();

    const float* Ag = A  + (size_t)(row0 + lane) * N_DIM;
    const float* Bg = Bw + (size_t)(col0 + lane) * N_DIM;
    const int kw = w * BK;
    double* cbuf = (double*)smem;                // 4096 doubles = 32KB
    double* rbuf = (double*)(smem + 32768);      // 64 doubles (row-sum xchg)
    double rsum = 0.0;

    if (fh <= 15u) {
        // ================= MFMA path =================
        const int dF = fh & 3, ab = fh >> 2;
        const int aF = ab & 1, bF = (ab >> 1) & 1;
        const int mA = aF ? (lane >> 2) : (lane & 15);
        const int kA = aF ? (lane & 3)  : (lane >> 4);
        const int nB = bF ? (lane >> 2) : (lane & 15);
        const int kB = bF ? (lane & 3)  : (lane >> 4);
        int iD[4], jD[4];
#pragma unroll
        for (int r = 0; r < 4; ++r) {
            if (dF == 0)      { iD[r] = 4 * (lane >> 4) + r; jD[r] = lane & 15; }
            else if (dF == 1) { iD[r] = (lane >> 4) + 4 * r; jD[r] = lane & 15; }
            else if (dF == 2) { jD[r] = 4 * (lane >> 4) + r; iD[r] = lane & 15; }
            else              { jD[r] = (lane >> 4) + 4 * r; iD[r] = lane & 15; }
        }

        float* A0 = (float*)(smem + (size_t)w * 20480);  // 16 x 80 floats
        float* B0 = A0 + 1280;
        float* A1 = A0 + 2560;
        float* B1 = A0 + 3840;

        d4 acc[4][4];
#pragma unroll
        for (int f = 0; f < 4; ++f)
#pragma unroll
            for (int g = 0; g < 4; ++g) acc[f][g] = (d4)0.0;

        float4 sa[4], sb[4];
        MFMA_LOAD(kw)                 // tile 0
        MFMA_STAGE(A0, B0)            // -> buf0
        MFMA_LOAD(kw + 32)            // tile 1

        for (int k0 = kw; k0 < N_DIM; k0 += 64) {
            MFMA_STAGE(A1, B1)        // tile k0+32 -> buf1
            if (k0 + 64 < N_DIM) { MFMA_LOAD(k0 + 64) }
            MFMA_COMPUTE(A0, B0)      // tile k0
            if (k0 + 64 < N_DIM) {
                MFMA_STAGE(A0, B0)    // tile k0+64 -> buf0
                if (k0 + 96 < N_DIM) { MFMA_LOAD(k0 + 96) }
            }
            MFMA_COMPUTE(A1, B1)      // tile k0+32
        }

        __syncthreads();
        if (w == 1) {
#pragma unroll
            for (int f = 0; f < 4; ++f)
#pragma unroll
                for (int g = 0; g < 4; ++g)
#pragma unroll
                    for (int r = 0; r < 4; ++r)
                        cbuf[((f * 4 + g) * 4 + r) * 64 + lane] = acc[f][g][r];
            if (do_rsum) rbuf[lane] = rsum;
        }
        __syncthreads();
        if (w == 0) {
#pragma unroll
            for (int f = 0; f < 4; ++f)
#pragma unroll
                for (int g = 0; g < 4; ++g)
#pragma unroll
                    for (int r = 0; r < 4; ++r)
                        acc[f][g][r] += cbuf[((f * 4 + g) * 4 + r) * 64 + lane];
            // store C (f32)
#pragma unroll
            for (int f = 0; f < 4; ++f)
#pragma unroll
                for (int r = 0; r < 4; ++r) {
                    int row = row0 + 16 * f + iD[r];
                    float* Crow = C + (size_t)row * N_DIM + col0 + jD[r];
#pragma unroll
                    for (int g = 0; g < 4; ++g)
                        Crow[16 * g] = (float)acc[f][g][r];
                }
            // layout-agnostic BN partials: scatter acc -> cbuf[row][col],
            // then column-sum (same-wave DS ordering -> no barrier needed)
#pragma unroll
            for (int f = 0; f < 4; ++f)
#pragma unroll
                for (int r = 0; r < 4; ++r)
#pragma unroll
                    for (int g = 0; g < 4; ++g)
                        cbuf[(16 * f + iD[r]) * 64 + 16 * g + jD[r]] = acc[f][g][r];
            double s = 0.0, q = 0.0;
#pragma unroll
            for (int r = 0; r < 64; ++r) {
                double v = cbuf[r * 64 + lane];
                s += v;
                q = fma(v, v, q);
            }
            psum [band * N_DIM + col0 + lane] = s;
            psum2[band * N_DIM + col0 + lane] = q;
            if (do_rsum) ssum_out[row0 + lane] = rsum + rbuf[lane];
        }
    } else {
        // ================= f64 VALU fallback (probe-fail only) =================
        const int tx = lane & 7;
        const int ty = lane >> 3;
        double* Asd = (double*)smem + (size_t)w * 2176;  // 16 x 68 doubles
        double* Bsd = Asd + 1088;

        double acc[8][8];
#pragma unroll
        for (int i = 0; i < 8; ++i)
#pragma unroll
            for (int j = 0; j < 8; ++j) acc[i][j] = 0.0;

        float4 sa[4], sb[4];
#pragma unroll
        for (int j = 0; j < 4; ++j) {
            sa[j] = *(const float4*)(Ag + kw + 4 * j);
            sb[j] = *(const float4*)(Bg + kw + 4 * j);
        }
        for (int k0 = kw; k0 < N_DIM; k0 += 2 * BK) {
#pragma unroll
            for (int j = 0; j < 4; ++j) {
                Asd[(4 * j + 0) * SDD + lane] = (double)sa[j].x;
                Asd[(4 * j + 1) * SDD + lane] = (double)sa[j].y;
                Asd[(4 * j + 2) * SDD + lane] = (double)sa[j].z;
                Asd[(4 * j + 3) * SDD + lane] = (double)sa[j].w;
                Bsd[(4 * j + 0) * SDD + lane] = (double)sb[j].x;
                Bsd[(4 * j + 1) * SDD + lane] = (double)sb[j].y;
                Bsd[(4 * j + 2) * SDD + lane] = (double)sb[j].z;
                Bsd[(4 * j + 3) * SDD + lane] = (double)sb[j].w;
            }
            if (do_rsum) {
#pragma unroll
                for (int j = 0; j < 4; ++j)
                    rsum += (double)sa[j].x + (double)sa[j].y +
                            (double)sa[j].z + (double)sa[j].w;
            }
            if (k0 + 2 * BK < N_DIM) {
#pragma unroll
                for (int j = 0; j < 4; ++j) {
                    sa[j] = *(const float4*)(Ag + k0 + 2 * BK + 4 * j);
                    sb[j] = *(const float4*)(Bg + k0 + 2 * BK + 4 * j);
                }
            }
#pragma unroll
            for (int k = 0; k < BK; ++k) {
                double a[8], b[8];
#pragma unroll
                for (int e = 0; e < 4; ++e) {
                    a[e]     = Asd[k * SDD + 4 * ty + e];
                    a[e + 4] = Asd[k * SDD + 32 + 4 * ty + e];
                    b[e]     = Bsd[k * SDD + 4 * tx + e];
                    b[e + 4] = Bsd[k * SDD + 32 + 4 * tx + e];
                }
#pragma unroll
                for (int i = 0; i < 8; ++i)
#pragma unroll
                    for (int j = 0; j < 8; ++j)
                        acc[i][j] = fma(a[i], b[j], acc[i][j]);
            }
        }

        __syncthreads();
        if (w == 1) {
#pragma unroll
            for (int e = 0; e < 64; ++e)
                cbuf[e * 64 + lane] = acc[e >> 3][e & 7];
            if (do_rsum) rbuf[lane] = rsum;
        }
        __syncthreads();
        if (w == 0) {
#pragma unroll
            for (int i = 0; i < 8; ++i)
#pragma unroll
                for (int j = 0; j < 8; ++j)
                    acc[i][j] += cbuf[(i * 8 + j) * 64 + lane];
#pragma unroll
            for (int i = 0; i < 8; ++i) {
                int r = row0 + ((i < 4) ? (4 * ty + i) : (32 + 4 * ty + i - 4));
                float* Crow = C + (size_t)r * N_DIM + col0;
#pragma unroll
                for (int jg = 0; jg < 2; ++jg) {
                    int cbase = (jg == 0) ? (4 * tx) : (32 + 4 * tx);
                    float4 v;
                    v.x = (float)acc[i][4 * jg + 0]; v.y = (float)acc[i][4 * jg + 1];
                    v.z = (float)acc[i][4 * jg + 2]; v.w = (float)acc[i][4 * jg + 3];
                    *(float4*)(Crow + cbase) = v;
                }
            }
            // BN partials via cbuf scatter + column reduction
#pragma unroll
            for (int i = 0; i < 8; ++i) {
                int rr = (i < 4) ? (4 * ty + i) : (32 + 4 * ty + i - 4);
#pragma unroll
                for (int j = 0; j < 8; ++j) {
                    int cc = (j < 4) ? (4 * tx + j) : (32 + 4 * tx + j - 4);
                    cbuf[rr * 64 + cc] = acc[i][j];
                }
            }
            double s = 0.0, q = 0.0;
#pragma unroll
            for (int r = 0; r < 64; ++r) {
                double v = cbuf[r * 64 + lane];
                s += v;
                q = fma(v, v, q);
            }
            psum [band * N_DIM + col0 + lane] = s;
            psum2[band * N_DIM + col0 + lane] = q;
            if (do_rsum) ssum_out[row0 + lane] = rsum + rbuf[lane];
        }
    }
}

// ---- fused BN-final + BN-apply + temporal-sum + triple LIF + output -------
// Absorbs col_stats_final (scale/shift re-derived per thread from the
// L2-resident 1MB psum/psum2) and temporal_sum (computed from the x values
// this thread must load anyway; x cached in 16 regs, killing the re-read).
__global__ __launch_bounds__(256)
void fused_lif_kernel(const float* __restrict__ x, const float* __restrict__ h,
                      const double* __restrict__ psum, const double* __restrict__ psum2,
                      const float* __restrict__ gamma, const float* __restrict__ beta,
                      const double* __restrict__ ssum, float* __restrict__ out) {
    int idx = blockIdx.x * 256 + threadIdx.x;
    int n = idx & (N_DIM - 1);
    int b = idx >> 11;
    // BN scale/shift for this column
    double s = 0.0, s2 = 0.0;
#pragma unroll
    for (int c = 0; c < 32; ++c) {
        s  += psum [c * N_DIM + n];
        s2 += psum2[c * N_DIM + n];
    }
    double mean = s * (1.0 / 2048.0);
    double var  = s2 * (1.0 / 2048.0) - mean * mean;
    double istd = 1.0 / sqrt(var + 1e-5);
    double sc = istd * (double)gamma[n];
    double sh = (double)beta[n] - mean * sc;
    // temporal sum (ascending t, f64)
    float xv[T_DIM];
    double ts = 0.0;
#pragma unroll
    for (int t = 0; t < T_DIM; ++t) {
        xv[t] = x[(size_t)(t * B_DIM + b) * N_DIM + n];
        ts += (double)xv[t];
    }
    double v1 = 0.0, v2 = 0.0, v3 = 0.0;
#pragma unroll
    for (int t = 0; t < T_DIM; ++t) {
        size_t off = (size_t)(t * B_DIM + b) * N_DIM + n;
        double hv = fma((double)h[off], sc, sh);
        v1 = v1 * 0.5 + hv;
        bool s1 = (v1 >= 1.0); if (s1) v1 = 0.0;
        double in2 = s1 ? ssum[t * B_DIM + b] : 0.0;
        v2 = v2 * 0.5 + in2;
        bool s2b = (v2 >= 1.0); if (s2b) v2 = 0.0;
        double in3 = s1 ? ts : 0.0;
        v3 = v3 * 0.5 + in3;
        bool s3 = (v3 >= 1.0); if (s3) v3 = 0.0;
        out[off] = xv[t] + ((s2b && s3) ? 1.0f : 0.0f);
    }
}

extern "C" void kernel_launch(void* const* d_in, const int* in_sizes, int n_in,
                              void* d_out, int out_size, void* d_ws, size_t ws_size,
                              hipStream_t stream) {
    const float* x     = (const float*)d_in[0];   // [16,128,2048]
    const float* W     = (const float*)d_in[1];   // [2048,2048]
    const float* gamma = (const float*)d_in[2];   // [2048]
    const float* beta  = (const float*)d_in[3];   // [2048]
    float* out = (float*)d_out;

    char* ws = (char*)d_ws;
    float*  h     = (float*)(ws + WS_H);
    double* psum  = (double*)(ws + WS_PSUM);
    double* psum2 = (double*)(ws + WS_PSUM2);
    double* ssum  = (double*)(ws + WS_SSUM);

    gemm_hybrid<<<dim3(N_DIM / 64, TB / 64), 128, 0, stream>>>(x, W, h, psum, psum2, ssum);
    fused_lif_kernel<<<(B_DIM * N_DIM) / 256, 256, 0, stream>>>(
        x, h, psum, psum2, gamma, beta, ssum, out);
}